// Round 16
// baseline (192.206 us; speedup 1.0000x reference)
//
#include <hip/hip_runtime.h>
#include <stdint.h>

typedef __attribute__((ext_vector_type(8))) _Float16 f16x8;
typedef __attribute__((ext_vector_type(4))) float f32x4;
typedef __attribute__((ext_vector_type(16))) float f32x16;

#define MFMA16F(a, b, c) __builtin_amdgcn_mfma_f32_16x16x32_f16((a), (b), (c), 0, 0, 0)
#define MFMA32F(a, b, c) __builtin_amdgcn_mfma_f32_32x32x16_f16((a), (b), (c), 0, 0, 0)

static constexpr int NT = 4096;   // tokens
static constexpr int DM = 1024;   // model dim
static constexpr int NH = 16;     // heads
static constexpr int DH = 64;     // head dim
static constexpr int NB = 3072;   // qkv output cols
static constexpr int PARTB = 128 * 64 * 2 + 1024;  // bytes/partial: fp16 O + f32 m,l

__device__ __forceinline__ unsigned short f2h(float f) {
  union { _Float16 h; unsigned short u; } v; v.h = (_Float16)f; return v.u;
}
__device__ __forceinline__ float h2f(unsigned short u) {
  union { _Float16 h; unsigned short u; } v; v.u = u; return (float)v.h;
}
__device__ __forceinline__ f32x16 splat16(float x) {
  f32x16 z;
#pragma unroll
  for (int i = 0; i < 16; ++i) z[i] = x;
  return z;
}
// direct global->LDS 16B copy (lane i lands at ldsbase + i*16)
__device__ __forceinline__ void gl2lds16(const void* g, void* l) {
  auto gp = (const __attribute__((address_space(1))) uint32_t*)(uintptr_t)g;
  auto lp = (__attribute__((address_space(3))) uint32_t*)(uint32_t)(uintptr_t)l;
  __builtin_amdgcn_global_load_lds(gp, lp, 16, 0, 0);
}
// swizzled byte offset inside a [128][32]-fp16 linear tile
__device__ __forceinline__ int swzoff(int row, int g) {
  return row * 64 + (((g ^ (row >> 1)) & 3) << 4);
}

// ---------------- transpose fp32 weights -> fp16 [N][K] ----------------
__global__ __launch_bounds__(256) void k_transpose_half(
    const float* __restrict__ src, int K, int N, unsigned short* __restrict__ dst) {
  __shared__ float tile[64][65];
  const int tk = blockIdx.x * 64;
  const int tn = blockIdx.y * 64;
  const int t = threadIdx.x;
  const int rr = t >> 4, cc = (t & 15) * 4;
#pragma unroll
  for (int p = 0; p < 4; ++p) {
    int r = rr + p * 16;
    const float4 v = *reinterpret_cast<const float4*>(&src[(size_t)(tk + r) * N + tn + cc]);
    tile[r][cc] = v.x; tile[r][cc + 1] = v.y; tile[r][cc + 2] = v.z; tile[r][cc + 3] = v.w;
  }
  __syncthreads();
#pragma unroll
  for (int p = 0; p < 4; ++p) {
    int r = rr + p * 16;  // n offset
    size_t o = (size_t)(tn + r) * K + tk + cc;
    *reinterpret_cast<ushort4*>(&dst[o]) =
        make_ushort4(f2h(tile[cc + 0][r]), f2h(tile[cc + 1][r]),
                     f2h(tile[cc + 2][r]), f2h(tile[cc + 3][r]));
  }
}

// ---------------- RMSNorm (L2-normalize * sqrt(dim) * gamma) -> fp16 ----------------
__global__ __launch_bounds__(256) void k_rmsnorm_half(
    const float* __restrict__ x, const float* __restrict__ gamma,
    unsigned short* __restrict__ xh) {
  const int row = blockIdx.x;
  const int t = threadIdx.x;
  const float4 v = reinterpret_cast<const float4*>(x + (size_t)row * DM)[t];
  float ss = v.x * v.x + v.y * v.y + v.z * v.z + v.w * v.w;
#pragma unroll
  for (int m = 1; m <= 32; m <<= 1) ss += __shfl_xor(ss, m);
  __shared__ float red[4];
  if ((t & 63) == 0) red[t >> 6] = ss;
  __syncthreads();
  float tot = red[0] + red[1] + red[2] + red[3];
  float inv = 32.0f * rsqrtf(fmaxf(tot, 1e-24f));
  const float4 g = reinterpret_cast<const float4*>(gamma)[t];
  *reinterpret_cast<ushort4*>(&xh[(size_t)row * DM + t * 4]) =
      make_ushort4(f2h(v.x * inv * g.x), f2h(v.y * inv * g.y),
                   f2h(v.z * inv * g.z), f2h(v.w * inv * g.w));
}

// ---------------- QKV GEMM: plain fp16; global_load_lds staging, swizzled LDS ----------
__global__ __launch_bounds__(256) void k_qkv_gemm(
    const unsigned short* __restrict__ xh, const unsigned short* __restrict__ wh,
    unsigned short* __restrict__ qh, unsigned short* __restrict__ kh,
    unsigned short* __restrict__ vvT) {
  __shared__ unsigned short sA[128 * 32], sB[128 * 32];
  const int t = threadIdx.x;
  const int l = t & 63, w = t >> 6;
  const int g = l >> 4, li = l & 15;
  const int m0 = blockIdx.y * 128, n0 = blockIdx.x * 128;
  const int wm = (w >> 1) * 64, wn = (w & 1) * 64;

  int srow[2], scol[2];
#pragma unroll
  for (int j = 0; j < 2; ++j) {
    int slot = w * 128 + j * 64 + l;
    srow[j] = slot >> 2;
    scol[j] = (((slot & 3) ^ (srow[j] >> 1)) & 3) * 8;
  }
  const int lb0 = __builtin_amdgcn_readfirstlane(w * 2048);  // wave-uniform LDS byte base

  f32x4 acc[4][4];
#pragma unroll
  for (int a = 0; a < 4; ++a)
#pragma unroll
    for (int b = 0; b < 4; ++b) acc[a][b] = f32x4{0.f, 0.f, 0.f, 0.f};

  for (int k0 = 0; k0 < DM; k0 += 32) {
    __syncthreads();  // previous compute's LDS reads done
#pragma unroll
    for (int j = 0; j < 2; ++j) {
      const int lb = lb0 + j * 1024;
      gl2lds16(&xh[(size_t)(m0 + srow[j]) * DM + k0 + scol[j]], (char*)sA + lb);
      gl2lds16(&wh[(size_t)(n0 + srow[j]) * DM + k0 + scol[j]], (char*)sB + lb);
    }
    __syncthreads();  // barrier drain -> tile visible
    f16x8 af[4];
#pragma unroll
    for (int mt = 0; mt < 4; ++mt)
      af[mt] = *(const f16x8*)((const char*)sA + swzoff(wm + mt * 16 + li, g));
#pragma unroll
    for (int nt = 0; nt < 4; ++nt) {
      f16x8 bf = *(const f16x8*)((const char*)sB + swzoff(wn + nt * 16 + li, g));
#pragma unroll
      for (int mt = 0; mt < 4; ++mt)
        acc[mt][nt] = MFMA16F(af[mt], bf, acc[mt][nt]);
    }
  }
  // epilogue: C/D layout col=lane&15, row=4*(lane>>4)+reg
#pragma unroll
  for (int mt = 0; mt < 4; ++mt)
#pragma unroll
    for (int nt = 0; nt < 4; ++nt)
#pragma unroll
      for (int r = 0; r < 4; ++r) {
        int row = m0 + wm + mt * 16 + 4 * g + r;
        int col = n0 + wn + nt * 16 + li;
        float val = acc[mt][nt][r];
        int which = col >> 10;
        int head = (col >> 6) & 15;
        int d = col & 63;
        if (which == 0) {
          // fold sqrt(dim_head)=8 AND log2(e) so softmax uses exp2
          qh[((size_t)head * NT + row) * DH + d] = f2h(val * 11.5415603f);
        } else if (which == 1) {
          kh[((size_t)head * NT + row) * DH + d] = f2h(val);
        } else {
          vvT[((size_t)head * DH + d) * NT + row] = f2h(val);  // [h][d][n]
        }
      }
}

// ---------------- causal flash attention: 32x32 fp16 MFMA, 128-q tiles, chunked KV -----
// 1008 blocks = 16 heads x 63 chunks. Seeded-max + __all defer + ptr-incremented staging.
__global__ __launch_bounds__(256) void k_attn(
    const unsigned short* __restrict__ qh, const unsigned short* __restrict__ kh,
    const unsigned short* __restrict__ vvT, unsigned short* __restrict__ oo,
    float* __restrict__ part) {
  __shared__ unsigned short sKh[64 * 64], sVt[64 * 64];
  const int t = threadIdx.x;
  const int l = t & 63, w = t >> 6;
  const int hl = l >> 5, l31 = l & 31;
  const int bid = blockIdx.x;
  const int hh = (bid & 7) * 2 + ((bid >> 3) & 1);  // 2 heads per XCD
  const int r = bid >> 4;                            // 0..62
  int qt, j, P;
  if (r < 11)      { qt = r;                 j = 0;            P = 1; }
  else if (r < 33) { qt = 11 + (r - 11) / 2; j = (r - 11) & 1; P = 2; }
  else             { qt = 22 + (r - 33) / 3; j = (r - 33) % 3; P = 3; }
  const int n = 2 * qt + 2;
  const int kb0 = (j * n) / P, kb1 = ((j + 1) * n) / P - 1;
  const int q0 = qt * 128;
  const int qrow = q0 + w * 32 + l31;

  // Q fragments: lane(col=q=l31, half hl) supplies d = 16c + 8*hl + j
  size_t qoff = ((size_t)hh * NT + qrow) * DH;
  f16x8 qf[4];
#pragma unroll
  for (int c = 0; c < 4; ++c)
    qf[c] = *(const f16x8*)&qh[qoff + c * 16 + hl * 8];

  f32x16 oacc[2];
  oacc[0] = splat16(0.f); oacc[1] = splat16(0.f);
  float mrun = -INFINITY, lsum = 0.f;

  // staging: 2 chunks/thread/array; pointer-incremented (K += 64*DH, V += 64 per tile)
  f16x8 rk[2], rv[2];
  const int srow0 = t >> 3, srow1 = (t + 256) >> 3, sslot = t & 7;
  const unsigned short* pk0 = &kh[((size_t)hh * NT + kb0 * 64 + srow0) * DH + sslot * 8];
  const unsigned short* pk1 = &kh[((size_t)hh * NT + kb0 * 64 + srow1) * DH + sslot * 8];
  const unsigned short* pv0 = &vvT[((size_t)hh * DH + srow0) * NT + kb0 * 64 + sslot * 8];
  const unsigned short* pv1 = &vvT[((size_t)hh * DH + srow1) * NT + kb0 * 64 + sslot * 8];
  auto LOADP = [&]() {
    rk[0] = *(const f16x8*)pk0;  rk[1] = *(const f16x8*)pk1;
    rv[0] = *(const f16x8*)pv0;  rv[1] = *(const f16x8*)pv1;
    pk0 += 64 * DH;  pk1 += 64 * DH;  pv0 += 64;  pv1 += 64;
  };
  const int lw0 = srow0 * 128 + ((sslot ^ (srow0 & 7)) * 16);
  const int lw1 = srow1 * 128 + ((sslot ^ (srow1 & 7)) * 16);

  LOADP();
  for (int kb = kb0; kb <= kb1; ++kb) {
    const int kv0 = kb * 64;
    __syncthreads();
    *(f16x8*)((char*)sKh + lw0) = rk[0];  *(f16x8*)((char*)sKh + lw1) = rk[1];
    *(f16x8*)((char*)sVt + lw0) = rv[0];  *(f16x8*)((char*)sVt + lw1) = rv[1];
    __syncthreads();
    if (kb < kb1) LOADP();

    if (kv0 > q0 + w * 32 + 31) continue;  // wave entirely above diagonal

    // S^T = K * Q^T, accumulator seeded with -mseed (folds max-subtraction into MFMA)
    const float mseed = (mrun == -INFINITY) ? 0.f : mrun;
    f32x16 s[2];
#pragma unroll
    for (int kvt = 0; kvt < 2; ++kvt) {
      f32x16 sv = splat16(-mseed);
      const int rowk = kvt * 32 + l31;
      const int rb = rowk * 128;
#pragma unroll
      for (int c = 0; c < 4; ++c) {
        const int sl = ((2 * c + hl) ^ (rowk & 7)) * 16;
        f16x8 ah = *(const f16x8*)((const char*)sKh + rb + sl);
        sv = MFMA32F(ah, qf[c], sv);
      }
      s[kvt] = sv;
    }
    if (kv0 + 63 > q0 + w * 32) {  // wave touches diagonal iff max kv > MIN q-row
#pragma unroll
      for (int kvt = 0; kvt < 2; ++kvt)
#pragma unroll
        for (int reg = 0; reg < 16; ++reg) {
          int kv = kv0 + kvt * 32 + (reg & 3) + 8 * (reg >> 2) + 4 * hl;
          if (kv > qrow) s[kvt][reg] = -INFINITY;
        }
    }
    // relative max via max3-shaped tree (s is qk - mseed)
    float m3[11];
#pragma unroll
    for (int i = 0; i < 10; ++i) {
      float a = s[(3 * i) >> 4][(3 * i) & 15];
      float b = s[(3 * i + 1) >> 4][(3 * i + 1) & 15];
      float c = s[(3 * i + 2) >> 4][(3 * i + 2) & 15];
      m3[i] = fmaxf(fmaxf(a, b), c);
    }
    m3[10] = fmaxf(s[1][14], s[1][15]);
    float a0 = fmaxf(fmaxf(m3[0], m3[1]), m3[2]);
    float a1 = fmaxf(fmaxf(m3[3], m3[4]), m3[5]);
    float a2 = fmaxf(fmaxf(m3[6], m3[7]), m3[8]);
    float a3 = fmaxf(m3[9], m3[10]);
    float vrel = fmaxf(fmaxf(a0, a1), fmaxf(a2, a3));
    vrel = fmaxf(vrel, __shfl_xor(vrel, 32));
    bool defer = (mrun != -INFINITY) && (vrel <= 11.0f);
    if (!__all(defer)) {  // wave-uniform rescale path
      float mnew = fmaxf(mrun, vrel + mseed);
      float sc = exp2f(mrun - mnew);
      lsum *= sc;
#pragma unroll
      for (int dt = 0; dt < 2; ++dt)
#pragma unroll
        for (int reg = 0; reg < 16; ++reg) oacc[dt][reg] *= sc;
      float delta = mnew - mseed;
#pragma unroll
      for (int kvt = 0; kvt < 2; ++kvt)
#pragma unroll
        for (int reg = 0; reg < 16; ++reg) s[kvt][reg] -= delta;
      mrun = mnew;
    }
    // p = exp2(s)  (defer path: zero subtractions)
#pragma unroll
    for (int kvt = 0; kvt < 2; ++kvt)
#pragma unroll
      for (int reg = 0; reg < 16; ++reg) s[kvt][reg] = exp2f(s[kvt][reg]);
    float sm[16];
#pragma unroll
    for (int i = 0; i < 16; ++i) sm[i] = s[0][i] + s[1][i];
#pragma unroll
    for (int st = 8; st >= 1; st >>= 1)
#pragma unroll
      for (int i = 0; i < 8; ++i)
        if (i < st) sm[i] += sm[i + st];
    lsum += sm[0] + __shfl_xor(sm[0], 32);

    // P fragments (pi-packing): chunk c slot jj <-> kv = 16c + 4*hl + (jj&3) + 8*(jj>>2)
    union U8 { _Float16 e[8]; f16x8 v; } pf[4];
#pragma unroll
    for (int c = 0; c < 4; ++c)
#pragma unroll
      for (int jj = 0; jj < 8; ++jj)
        pf[c].e[jj] = (_Float16)s[c >> 1][(jj & 3) + 4 * (jj >> 2) + 8 * (c & 1)];

    // O^T += V^T * P^T: A = V^T (row=d=l31), same pi k-mapping -> two b64 per chunk
#pragma unroll
    for (int dt = 0; dt < 2; ++dt) {
      const int rowv = dt * 32 + l31;
      const int rb = rowv * 128;
#pragma unroll
      for (int c = 0; c < 4; ++c) {
        const int s0 = (((2 * c) ^ (rowv & 7)) * 16) + 8 * hl;
        const int s1 = (((2 * c + 1) ^ (rowv & 7)) * 16) + 8 * hl;
        union U8 vf;
        *(ushort4*)&vf.e[0] = *(const ushort4*)((const char*)sVt + rb + s0);
        *(ushort4*)&vf.e[4] = *(const ushort4*)((const char*)sVt + rb + s1);
        oacc[dt] = MFMA32F(vf.v, pf[c].v, oacc[dt]);
      }
    }
  }
  // epilogue: O^T lane: col=q=l31, row d = dt*32 + 4*hl + 8*rr + (0..3)
  if (P == 1) {
    float inv = 1.0f / lsum;
#pragma unroll
    for (int dt = 0; dt < 2; ++dt)
#pragma unroll
      for (int rr = 0; rr < 4; ++rr) {
        ushort4 o4 = make_ushort4(f2h(oacc[dt][4 * rr + 0] * inv), f2h(oacc[dt][4 * rr + 1] * inv),
                                  f2h(oacc[dt][4 * rr + 2] * inv), f2h(oacc[dt][4 * rr + 3] * inv));
        *(ushort4*)&oo[(size_t)qrow * DM + hh * 64 + dt * 32 + 8 * rr + 4 * hl] = o4;
      }
  } else {
    const int sb = (qt <= 21) ? (qt - 11) * 2 : 22 + (qt - 22) * 3;  // compact slots
    char* pb = (char*)part + (size_t)(hh * 52 + sb + j) * PARTB;
    unsigned short* po = (unsigned short*)pb;
    float* pm = (float*)(pb + 16384);
    const int qr = w * 32 + l31;
#pragma unroll
    for (int dt = 0; dt < 2; ++dt)
#pragma unroll
      for (int rr = 0; rr < 4; ++rr) {
        ushort4 o4 = make_ushort4(f2h(oacc[dt][4 * rr + 0]), f2h(oacc[dt][4 * rr + 1]),
                                  f2h(oacc[dt][4 * rr + 2]), f2h(oacc[dt][4 * rr + 3]));
        *(ushort4*)&po[qr * 64 + dt * 32 + 8 * rr + 4 * hl] = o4;
      }
    if (hl == 0) { pm[qr] = mrun; pm[128 + qr] = lsum; }
  }
}

// ---------------- merge KV-chunk partials for tiles qt in [11,31] ----------------
__global__ __launch_bounds__(256) void k_merge(const float* __restrict__ part,
                                               unsigned short* __restrict__ oo) {
  const int mb = blockIdx.x;  // 16 heads x 21 tiles
  const int hh = mb / 21, qt = 11 + mb % 21;
  const int P = (qt <= 21) ? 2 : 3;
  const int sb = (qt <= 21) ? (qt - 11) * 2 : 22 + (qt - 22) * 3;
  const char* base = (const char*)part + (size_t)(hh * 52 + sb) * PARTB;
  const int t = threadIdx.x;
  const int row = t >> 1, d0 = (t & 1) * 32;
  float mm = -INFINITY;
  for (int p = 0; p < P; ++p)
    mm = fmaxf(mm, *(const float*)(base + p * PARTB + 16384 + row * 4));
  float denom = 0.f;
  for (int p = 0; p < P; ++p) {
    float mp = *(const float*)(base + p * PARTB + 16384 + row * 4);
    float lp = *(const float*)(base + p * PARTB + 16384 + 512 + row * 4);
    denom += exp2f(mp - mm) * lp;
  }
  float inv = 1.0f / denom;
  const size_t orow = (size_t)(qt * 128 + row) * DM + hh * 64 + d0;
#pragma unroll
  for (int dd = 0; dd < 32; dd += 4) {
    float a0 = 0, a1 = 0, a2 = 0, a3 = 0;
    for (int p = 0; p < P; ++p) {
      float wp = exp2f(*(const float*)(base + p * PARTB + 16384 + row * 4) - mm);
      ushort4 u = *(const ushort4*)(base + p * PARTB + (size_t)(row * 64 + d0 + dd) * 2);
      a0 += wp * h2f(u.x); a1 += wp * h2f(u.y); a2 += wp * h2f(u.z); a3 += wp * h2f(u.w);
    }
    *(ushort4*)&oo[orow + dd] = make_ushort4(f2h(a0 * inv), f2h(a1 * inv),
                                             f2h(a2 * inv), f2h(a3 * inv));
  }
}

// ---------------- out projection: fp16, global_load_lds staging, swizzled LDS ----------
__global__ __launch_bounds__(256) void k_out_gemm(
    const unsigned short* __restrict__ A, const unsigned short* __restrict__ Bt,
    float* __restrict__ C) {
  __shared__ unsigned short sA[128 * 32], sB[128 * 32];
  const int t = threadIdx.x;
  const int l = t & 63, w = t >> 6;
  const int g = l >> 4, li = l & 15;
  const int m0 = blockIdx.y * 128, n0 = blockIdx.x * 128;
  const int wm = (w >> 1) * 64, wn = (w & 1) * 64;

  int srow[2], scol[2];
#pragma unroll
  for (int j = 0; j < 2; ++j) {
    int slot = w * 128 + j * 64 + l;
    srow[j] = slot >> 2;
    scol[j] = (((slot & 3) ^ (srow[j] >> 1)) & 3) * 8;
  }
  const int lb0 = __builtin_amdgcn_readfirstlane(w * 2048);

  f32x4 acc[4][4];
#pragma unroll
  for (int a = 0; a < 4; ++a)
#pragma unroll
    for (int b = 0; b < 4; ++b) acc[a][b] = f32x4{0.f, 0.f, 0.f, 0.f};

  for (int k0 = 0; k0 < DM; k0 += 32) {
    __syncthreads();
#pragma unroll
    for (int j = 0; j < 2; ++j) {
      const int lb = lb0 + j * 1024;
      gl2lds16(&A[(size_t)(m0 + srow[j]) * DM + k0 + scol[j]], (char*)sA + lb);
      gl2lds16(&Bt[(size_t)(n0 + srow[j]) * DM + k0 + scol[j]], (char*)sB + lb);
    }
    __syncthreads();
    f16x8 af[4];
#pragma unroll
    for (int mt = 0; mt < 4; ++mt)
      af[mt] = *(const f16x8*)((const char*)sA + swzoff(wm + mt * 16 + li, g));
#pragma unroll
    for (int nt = 0; nt < 4; ++nt) {
      f16x8 bf = *(const f16x8*)((const char*)sB + swzoff(wn + nt * 16 + li, g));
#pragma unroll
      for (int mt = 0; mt < 4; ++mt)
        acc[mt][nt] = MFMA16F(af[mt], bf, acc[mt][nt]);
    }
  }
#pragma unroll
  for (int mt = 0; mt < 4; ++mt)
#pragma unroll
    for (int nt = 0; nt < 4; ++nt)
#pragma unroll
      for (int r = 0; r < 4; ++r) {
        int row = m0 + wm + mt * 16 + 4 * g + r;
        int col = n0 + wn + nt * 16 + li;
        C[(size_t)row * DM + col] = acc[mt][nt][r];
      }
}

extern "C" void kernel_launch(void* const* d_in, const int* in_sizes, int n_in,
                              void* d_out, int out_size, void* d_ws, size_t ws_size,
                              hipStream_t stream) {
  const float* x     = (const float*)d_in[0];
  const float* gamma = (const float*)d_in[1];
  const float* wqkv  = (const float*)d_in[2];
  const float* wout  = (const float*)d_in[3];
  float* out = (float*)d_out;

  char* ws = (char*)d_ws;
  size_t off = 0;
  auto alloc = [&](size_t n) { char* p = ws + off; off += (n + 255) & ~(size_t)255; return p; };

  unsigned short* xh  = (unsigned short*)alloc((size_t)NT * DM * 2);
  unsigned short* wqh = (unsigned short*)alloc((size_t)NB * DM * 2);
  unsigned short* qhp = (unsigned short*)alloc((size_t)NH * NT * DH * 2);
  unsigned short* khp = (unsigned short*)alloc((size_t)NH * NT * DH * 2);
  unsigned short* vvT = (unsigned short*)alloc((size_t)NH * DH * NT * 2);
  unsigned short* ao  = (unsigned short*)alloc((size_t)NT * DM * 2);
  unsigned short* woT = (unsigned short*)alloc((size_t)DM * DM * 2);
  float*          prt = (float*)alloc((size_t)NH * 52 * PARTB);  // fp16 O + f32 m,l
  (void)ws_size; (void)in_sizes; (void)n_in; (void)out_size;

  k_transpose_half<<<dim3(DM / 64, NB / 64), 256, 0, stream>>>(wqkv, DM, NB, wqh);
  k_transpose_half<<<dim3(DM / 64, DM / 64), 256, 0, stream>>>(wout, DM, DM, woT);
  k_rmsnorm_half<<<NT, 256, 0, stream>>>(x, gamma, xh);
  k_qkv_gemm<<<dim3(NB / 128, NT / 128), 256, 0, stream>>>(xh, wqh, qhp, khp, vvT);
  k_attn<<<1008, 256, 0, stream>>>(qhp, khp, vvT, ao, prt);
  k_merge<<<16 * 21, 256, 0, stream>>>(prt, ao);
  k_out_gemm<<<dim3(DM / 128, NT / 128), 256, 0, stream>>>(ao, woT, out);
}

// Round 17
// 192.093 us; speedup vs baseline: 1.0006x; 1.0006x over previous
//
#include <hip/hip_runtime.h>
#include <stdint.h>

typedef __attribute__((ext_vector_type(8))) _Float16 f16x8;
typedef __attribute__((ext_vector_type(4))) float f32x4;
typedef __attribute__((ext_vector_type(16))) float f32x16;

#define MFMA16F(a, b, c) __builtin_amdgcn_mfma_f32_16x16x32_f16((a), (b), (c), 0, 0, 0)
#define MFMA32F(a, b, c) __builtin_amdgcn_mfma_f32_32x32x16_f16((a), (b), (c), 0, 0, 0)

static constexpr int NT = 4096;   // tokens
static constexpr int DM = 1024;   // model dim
static constexpr int NH = 16;     // heads
static constexpr int DH = 64;     // head dim
static constexpr int NB = 3072;   // qkv output cols
static constexpr int PARTB = 128 * 64 * 2 + 1024;  // bytes/partial: fp16 O + f32 m,l

__device__ __forceinline__ unsigned short f2h(float f) {
  union { _Float16 h; unsigned short u; } v; v.h = (_Float16)f; return v.u;
}
__device__ __forceinline__ float h2f(unsigned short u) {
  union { _Float16 h; unsigned short u; } v; v.u = u; return (float)v.h;
}
__device__ __forceinline__ f32x16 splat16(float x) {
  f32x16 z;
#pragma unroll
  for (int i = 0; i < 16; ++i) z[i] = x;
  return z;
}
// direct global->LDS 16B copy (lane i lands at ldsbase + i*16)
__device__ __forceinline__ void gl2lds16(const void* g, void* l) {
  auto gp = (const __attribute__((address_space(1))) uint32_t*)(uintptr_t)g;
  auto lp = (__attribute__((address_space(3))) uint32_t*)(uint32_t)(uintptr_t)l;
  __builtin_amdgcn_global_load_lds(gp, lp, 16, 0, 0);
}
// swizzled byte offset inside a [128][32]-fp16 linear tile
__device__ __forceinline__ int swzoff(int row, int g) {
  return row * 64 + (((g ^ (row >> 1)) & 3) << 4);
}

// ---------------- transpose fp32 weights -> fp16 [N][K] ----------------
__global__ __launch_bounds__(256) void k_transpose_half(
    const float* __restrict__ src, int K, int N, unsigned short* __restrict__ dst) {
  __shared__ float tile[64][65];
  const int tk = blockIdx.x * 64;
  const int tn = blockIdx.y * 64;
  const int t = threadIdx.x;
  const int rr = t >> 4, cc = (t & 15) * 4;
#pragma unroll
  for (int p = 0; p < 4; ++p) {
    int r = rr + p * 16;
    const float4 v = *reinterpret_cast<const float4*>(&src[(size_t)(tk + r) * N + tn + cc]);
    tile[r][cc] = v.x; tile[r][cc + 1] = v.y; tile[r][cc + 2] = v.z; tile[r][cc + 3] = v.w;
  }
  __syncthreads();
#pragma unroll
  for (int p = 0; p < 4; ++p) {
    int r = rr + p * 16;  // n offset
    size_t o = (size_t)(tn + r) * K + tk + cc;
    *reinterpret_cast<ushort4*>(&dst[o]) =
        make_ushort4(f2h(tile[cc + 0][r]), f2h(tile[cc + 1][r]),
                     f2h(tile[cc + 2][r]), f2h(tile[cc + 3][r]));
  }
}

// ---------------- RMSNorm (L2-normalize * sqrt(dim) * gamma) -> fp16 ----------------
__global__ __launch_bounds__(256) void k_rmsnorm_half(
    const float* __restrict__ x, const float* __restrict__ gamma,
    unsigned short* __restrict__ xh) {
  const int row = blockIdx.x;
  const int t = threadIdx.x;
  const float4 v = reinterpret_cast<const float4*>(x + (size_t)row * DM)[t];
  float ss = v.x * v.x + v.y * v.y + v.z * v.z + v.w * v.w;
#pragma unroll
  for (int m = 1; m <= 32; m <<= 1) ss += __shfl_xor(ss, m);
  __shared__ float red[4];
  if ((t & 63) == 0) red[t >> 6] = ss;
  __syncthreads();
  float tot = red[0] + red[1] + red[2] + red[3];
  float inv = 32.0f * rsqrtf(fmaxf(tot, 1e-24f));
  const float4 g = reinterpret_cast<const float4*>(gamma)[t];
  *reinterpret_cast<ushort4*>(&xh[(size_t)row * DM + t * 4]) =
      make_ushort4(f2h(v.x * inv * g.x), f2h(v.y * inv * g.y),
                   f2h(v.z * inv * g.z), f2h(v.w * inv * g.w));
}

// ---------------- QKV GEMM: plain fp16; global_load_lds staging, swizzled LDS ----------
__global__ __launch_bounds__(256) void k_qkv_gemm(
    const unsigned short* __restrict__ xh, const unsigned short* __restrict__ wh,
    unsigned short* __restrict__ qh, unsigned short* __restrict__ kh,
    unsigned short* __restrict__ vvT) {
  __shared__ unsigned short sA[128 * 32], sB[128 * 32];
  const int t = threadIdx.x;
  const int l = t & 63, w = t >> 6;
  const int g = l >> 4, li = l & 15;
  const int m0 = blockIdx.y * 128, n0 = blockIdx.x * 128;
  const int wm = (w >> 1) * 64, wn = (w & 1) * 64;

  int srow[2], scol[2];
#pragma unroll
  for (int j = 0; j < 2; ++j) {
    int slot = w * 128 + j * 64 + l;
    srow[j] = slot >> 2;
    scol[j] = (((slot & 3) ^ (srow[j] >> 1)) & 3) * 8;
  }
  const int lb0 = __builtin_amdgcn_readfirstlane(w * 2048);  // wave-uniform LDS byte base

  f32x4 acc[4][4];
#pragma unroll
  for (int a = 0; a < 4; ++a)
#pragma unroll
    for (int b = 0; b < 4; ++b) acc[a][b] = f32x4{0.f, 0.f, 0.f, 0.f};

  for (int k0 = 0; k0 < DM; k0 += 32) {
    __syncthreads();  // previous compute's LDS reads done
#pragma unroll
    for (int j = 0; j < 2; ++j) {
      const int lb = lb0 + j * 1024;
      gl2lds16(&xh[(size_t)(m0 + srow[j]) * DM + k0 + scol[j]], (char*)sA + lb);
      gl2lds16(&wh[(size_t)(n0 + srow[j]) * DM + k0 + scol[j]], (char*)sB + lb);
    }
    __syncthreads();  // barrier drain -> tile visible
    f16x8 af[4];
#pragma unroll
    for (int mt = 0; mt < 4; ++mt)
      af[mt] = *(const f16x8*)((const char*)sA + swzoff(wm + mt * 16 + li, g));
#pragma unroll
    for (int nt = 0; nt < 4; ++nt) {
      f16x8 bf = *(const f16x8*)((const char*)sB + swzoff(wn + nt * 16 + li, g));
#pragma unroll
      for (int mt = 0; mt < 4; ++mt)
        acc[mt][nt] = MFMA16F(af[mt], bf, acc[mt][nt]);
    }
  }
  // epilogue: C/D layout col=lane&15, row=4*(lane>>4)+reg
#pragma unroll
  for (int mt = 0; mt < 4; ++mt)
#pragma unroll
    for (int nt = 0; nt < 4; ++nt)
#pragma unroll
      for (int r = 0; r < 4; ++r) {
        int row = m0 + wm + mt * 16 + 4 * g + r;
        int col = n0 + wn + nt * 16 + li;
        float val = acc[mt][nt][r];
        int which = col >> 10;
        int head = (col >> 6) & 15;
        int d = col & 63;
        if (which == 0) {
          // fold sqrt(dim_head)=8 AND log2(e) so softmax uses exp2
          qh[((size_t)head * NT + row) * DH + d] = f2h(val * 11.5415603f);
        } else if (which == 1) {
          kh[((size_t)head * NT + row) * DH + d] = f2h(val);
        } else {
          vvT[((size_t)head * DH + d) * NT + row] = f2h(val);  // [h][d][n]
        }
      }
}

// ---------------- causal flash attention: 32x32 fp16 MFMA, 128-q tiles, chunked KV -----
// 1008 blocks = 16 heads x 63 chunks. Seeded-max + __all defer + ptr-incremented staging.
__global__ __launch_bounds__(256) void k_attn(
    const unsigned short* __restrict__ qh, const unsigned short* __restrict__ kh,
    const unsigned short* __restrict__ vvT, unsigned short* __restrict__ oo,
    float* __restrict__ part) {
  __shared__ unsigned short sKh[64 * 64], sVt[64 * 64];
  const int t = threadIdx.x;
  const int l = t & 63, w = t >> 6;
  const int hl = l >> 5, l31 = l & 31;
  const int bid = blockIdx.x;
  const int hh = (bid & 7) * 2 + ((bid >> 3) & 1);  // 2 heads per XCD
  const int r = bid >> 4;                            // 0..62
  int qt, j, P;
  if (r < 11)      { qt = r;                 j = 0;            P = 1; }
  else if (r < 33) { qt = 11 + (r - 11) / 2; j = (r - 11) & 1; P = 2; }
  else             { qt = 22 + (r - 33) / 3; j = (r - 33) % 3; P = 3; }
  const int n = 2 * qt + 2;
  const int kb0 = (j * n) / P, kb1 = ((j + 1) * n) / P - 1;
  const int q0 = qt * 128;
  const int qrow = q0 + w * 32 + l31;

  // Q fragments: lane(col=q=l31, half hl) supplies d = 16c + 8*hl + j
  size_t qoff = ((size_t)hh * NT + qrow) * DH;
  f16x8 qf[4];
#pragma unroll
  for (int c = 0; c < 4; ++c)
    qf[c] = *(const f16x8*)&qh[qoff + c * 16 + hl * 8];

  f32x16 oacc[2];
  oacc[0] = splat16(0.f); oacc[1] = splat16(0.f);
  float mrun = -INFINITY, lsum = 0.f;

  // staging: 2 chunks/thread/array; pointer-incremented (K += 64*DH, V += 64 per tile)
  f16x8 rk[2], rv[2];
  const int srow0 = t >> 3, srow1 = (t + 256) >> 3, sslot = t & 7;
  const unsigned short* pk0 = &kh[((size_t)hh * NT + kb0 * 64 + srow0) * DH + sslot * 8];
  const unsigned short* pk1 = &kh[((size_t)hh * NT + kb0 * 64 + srow1) * DH + sslot * 8];
  const unsigned short* pv0 = &vvT[((size_t)hh * DH + srow0) * NT + kb0 * 64 + sslot * 8];
  const unsigned short* pv1 = &vvT[((size_t)hh * DH + srow1) * NT + kb0 * 64 + sslot * 8];
  auto LOADP = [&]() {
    rk[0] = *(const f16x8*)pk0;  rk[1] = *(const f16x8*)pk1;
    rv[0] = *(const f16x8*)pv0;  rv[1] = *(const f16x8*)pv1;
    pk0 += 64 * DH;  pk1 += 64 * DH;  pv0 += 64;  pv1 += 64;
  };
  const int lw0 = srow0 * 128 + ((sslot ^ (srow0 & 7)) * 16);
  const int lw1 = srow1 * 128 + ((sslot ^ (srow1 & 7)) * 16);

  LOADP();
  for (int kb = kb0; kb <= kb1; ++kb) {
    const int kv0 = kb * 64;
    __syncthreads();
    *(f16x8*)((char*)sKh + lw0) = rk[0];  *(f16x8*)((char*)sKh + lw1) = rk[1];
    *(f16x8*)((char*)sVt + lw0) = rv[0];  *(f16x8*)((char*)sVt + lw1) = rv[1];
    __syncthreads();
    if (kb < kb1) LOADP();

    if (kv0 > q0 + w * 32 + 31) continue;  // wave entirely above diagonal

    // S^T = K * Q^T, accumulator seeded with -mseed (folds max-subtraction into MFMA)
    const float mseed = (mrun == -INFINITY) ? 0.f : mrun;
    f32x16 s[2];
#pragma unroll
    for (int kvt = 0; kvt < 2; ++kvt) {
      f32x16 sv = splat16(-mseed);
      const int rowk = kvt * 32 + l31;
      const int rb = rowk * 128;
#pragma unroll
      for (int c = 0; c < 4; ++c) {
        const int sl = ((2 * c + hl) ^ (rowk & 7)) * 16;
        f16x8 ah = *(const f16x8*)((const char*)sKh + rb + sl);
        sv = MFMA32F(ah, qf[c], sv);
      }
      s[kvt] = sv;
    }
    if (kv0 + 63 > q0 + w * 32) {  // wave touches diagonal iff max kv > MIN q-row
#pragma unroll
      for (int kvt = 0; kvt < 2; ++kvt)
#pragma unroll
        for (int reg = 0; reg < 16; ++reg) {
          int kv = kv0 + kvt * 32 + (reg & 3) + 8 * (reg >> 2) + 4 * hl;
          if (kv > qrow) s[kvt][reg] = -INFINITY;
        }
    }
    // relative max via max3-shaped tree (s is qk - mseed)
    float m3[11];
#pragma unroll
    for (int i = 0; i < 10; ++i) {
      float a = s[(3 * i) >> 4][(3 * i) & 15];
      float b = s[(3 * i + 1) >> 4][(3 * i + 1) & 15];
      float c = s[(3 * i + 2) >> 4][(3 * i + 2) & 15];
      m3[i] = fmaxf(fmaxf(a, b), c);
    }
    m3[10] = fmaxf(s[1][14], s[1][15]);
    float a0 = fmaxf(fmaxf(m3[0], m3[1]), m3[2]);
    float a1 = fmaxf(fmaxf(m3[3], m3[4]), m3[5]);
    float a2 = fmaxf(fmaxf(m3[6], m3[7]), m3[8]);
    float a3 = fmaxf(m3[9], m3[10]);
    float vrel = fmaxf(fmaxf(a0, a1), fmaxf(a2, a3));
    vrel = fmaxf(vrel, __shfl_xor(vrel, 32));
    bool defer = (mrun != -INFINITY) && (vrel <= 11.0f);
    if (!__all(defer)) {  // wave-uniform rescale path
      float mnew = fmaxf(mrun, vrel + mseed);
      float sc = exp2f(mrun - mnew);
      lsum *= sc;
#pragma unroll
      for (int dt = 0; dt < 2; ++dt)
#pragma unroll
        for (int reg = 0; reg < 16; ++reg) oacc[dt][reg] *= sc;
      float delta = mnew - mseed;
#pragma unroll
      for (int kvt = 0; kvt < 2; ++kvt)
#pragma unroll
        for (int reg = 0; reg < 16; ++reg) s[kvt][reg] -= delta;
      mrun = mnew;
    }
    // p = exp2(s)  (defer path: zero subtractions)
#pragma unroll
    for (int kvt = 0; kvt < 2; ++kvt)
#pragma unroll
      for (int reg = 0; reg < 16; ++reg) s[kvt][reg] = exp2f(s[kvt][reg]);
    float sm[16];
#pragma unroll
    for (int i = 0; i < 16; ++i) sm[i] = s[0][i] + s[1][i];
#pragma unroll
    for (int st = 8; st >= 1; st >>= 1)
#pragma unroll
      for (int i = 0; i < 8; ++i)
        if (i < st) sm[i] += sm[i + st];
    lsum += sm[0] + __shfl_xor(sm[0], 32);

    // P fragments (pi-packing): chunk c slot jj <-> kv = 16c + 4*hl + (jj&3) + 8*(jj>>2)
    union U8 { _Float16 e[8]; f16x8 v; } pf[4];
#pragma unroll
    for (int c = 0; c < 4; ++c)
#pragma unroll
      for (int jj = 0; jj < 8; ++jj)
        pf[c].e[jj] = (_Float16)s[c >> 1][(jj & 3) + 4 * (jj >> 2) + 8 * (c & 1)];

    // O^T += V^T * P^T: A = V^T (row=d=l31), same pi k-mapping -> two b64 per chunk
#pragma unroll
    for (int dt = 0; dt < 2; ++dt) {
      const int rowv = dt * 32 + l31;
      const int rb = rowv * 128;
#pragma unroll
      for (int c = 0; c < 4; ++c) {
        const int s0 = (((2 * c) ^ (rowv & 7)) * 16) + 8 * hl;
        const int s1 = (((2 * c + 1) ^ (rowv & 7)) * 16) + 8 * hl;
        union U8 vf;
        *(ushort4*)&vf.e[0] = *(const ushort4*)((const char*)sVt + rb + s0);
        *(ushort4*)&vf.e[4] = *(const ushort4*)((const char*)sVt + rb + s1);
        oacc[dt] = MFMA32F(vf.v, pf[c].v, oacc[dt]);
      }
    }
  }
  // epilogue: O^T lane: col=q=l31, row d = dt*32 + 4*hl + 8*rr + (0..3)
  if (P == 1) {
    float inv = 1.0f / lsum;
#pragma unroll
    for (int dt = 0; dt < 2; ++dt)
#pragma unroll
      for (int rr = 0; rr < 4; ++rr) {
        ushort4 o4 = make_ushort4(f2h(oacc[dt][4 * rr + 0] * inv), f2h(oacc[dt][4 * rr + 1] * inv),
                                  f2h(oacc[dt][4 * rr + 2] * inv), f2h(oacc[dt][4 * rr + 3] * inv));
        *(ushort4*)&oo[(size_t)qrow * DM + hh * 64 + dt * 32 + 8 * rr + 4 * hl] = o4;
      }
  } else {
    const int sb = (qt <= 21) ? (qt - 11) * 2 : 22 + (qt - 22) * 3;  // compact slots
    char* pb = (char*)part + (size_t)(hh * 52 + sb + j) * PARTB;
    unsigned short* po = (unsigned short*)pb;
    float* pm = (float*)(pb + 16384);
    const int qr = w * 32 + l31;
#pragma unroll
    for (int dt = 0; dt < 2; ++dt)
#pragma unroll
      for (int rr = 0; rr < 4; ++rr) {
        ushort4 o4 = make_ushort4(f2h(oacc[dt][4 * rr + 0]), f2h(oacc[dt][4 * rr + 1]),
                                  f2h(oacc[dt][4 * rr + 2]), f2h(oacc[dt][4 * rr + 3]));
        *(ushort4*)&po[qr * 64 + dt * 32 + 8 * rr + 4 * hl] = o4;
      }
    if (hl == 0) { pm[qr] = mrun; pm[128 + qr] = lsum; }
  }
}

// ---------------- merge KV-chunk partials for tiles qt in [11,31] ----------------
__global__ __launch_bounds__(256) void k_merge(const float* __restrict__ part,
                                               unsigned short* __restrict__ oo) {
  const int mb = blockIdx.x;  // 16 heads x 21 tiles
  const int hh = mb / 21, qt = 11 + mb % 21;
  const int P = (qt <= 21) ? 2 : 3;
  const int sb = (qt <= 21) ? (qt - 11) * 2 : 22 + (qt - 22) * 3;
  const char* base = (const char*)part + (size_t)(hh * 52 + sb) * PARTB;
  const int t = threadIdx.x;
  const int row = t >> 1, d0 = (t & 1) * 32;
  float mm = -INFINITY;
  for (int p = 0; p < P; ++p)
    mm = fmaxf(mm, *(const float*)(base + p * PARTB + 16384 + row * 4));
  float denom = 0.f;
  for (int p = 0; p < P; ++p) {
    float mp = *(const float*)(base + p * PARTB + 16384 + row * 4);
    float lp = *(const float*)(base + p * PARTB + 16384 + 512 + row * 4);
    denom += exp2f(mp - mm) * lp;
  }
  float inv = 1.0f / denom;
  const size_t orow = (size_t)(qt * 128 + row) * DM + hh * 64 + d0;
#pragma unroll
  for (int dd = 0; dd < 32; dd += 4) {
    float a0 = 0, a1 = 0, a2 = 0, a3 = 0;
    for (int p = 0; p < P; ++p) {
      float wp = exp2f(*(const float*)(base + p * PARTB + 16384 + row * 4) - mm);
      ushort4 u = *(const ushort4*)(base + p * PARTB + (size_t)(row * 64 + d0 + dd) * 2);
      a0 += wp * h2f(u.x); a1 += wp * h2f(u.y); a2 += wp * h2f(u.z); a3 += wp * h2f(u.w);
    }
    *(ushort4*)&oo[orow + dd] = make_ushort4(f2h(a0 * inv), f2h(a1 * inv),
                                             f2h(a2 * inv), f2h(a3 * inv));
  }
}

// ---------------- out projection: fp16, global_load_lds staging, swizzled LDS ----------
__global__ __launch_bounds__(256) void k_out_gemm(
    const unsigned short* __restrict__ A, const unsigned short* __restrict__ Bt,
    float* __restrict__ C) {
  __shared__ unsigned short sA[128 * 32], sB[128 * 32];
  const int t = threadIdx.x;
  const int l = t & 63, w = t >> 6;
  const int g = l >> 4, li = l & 15;
  const int m0 = blockIdx.y * 128, n0 = blockIdx.x * 128;
  const int wm = (w >> 1) * 64, wn = (w & 1) * 64;

  int srow[2], scol[2];
#pragma unroll
  for (int j = 0; j < 2; ++j) {
    int slot = w * 128 + j * 64 + l;
    srow[j] = slot >> 2;
    scol[j] = (((slot & 3) ^ (srow[j] >> 1)) & 3) * 8;
  }
  const int lb0 = __builtin_amdgcn_readfirstlane(w * 2048);

  f32x4 acc[4][4];
#pragma unroll
  for (int a = 0; a < 4; ++a)
#pragma unroll
    for (int b = 0; b < 4; ++b) acc[a][b] = f32x4{0.f, 0.f, 0.f, 0.f};

  for (int k0 = 0; k0 < DM; k0 += 32) {
    __syncthreads();
#pragma unroll
    for (int j = 0; j < 2; ++j) {
      const int lb = lb0 + j * 1024;
      gl2lds16(&A[(size_t)(m0 + srow[j]) * DM + k0 + scol[j]], (char*)sA + lb);
      gl2lds16(&Bt[(size_t)(n0 + srow[j]) * DM + k0 + scol[j]], (char*)sB + lb);
    }
    __syncthreads();
    f16x8 af[4];
#pragma unroll
    for (int mt = 0; mt < 4; ++mt)
      af[mt] = *(const f16x8*)((const char*)sA + swzoff(wm + mt * 16 + li, g));
#pragma unroll
    for (int nt = 0; nt < 4; ++nt) {
      f16x8 bf = *(const f16x8*)((const char*)sB + swzoff(wn + nt * 16 + li, g));
#pragma unroll
      for (int mt = 0; mt < 4; ++mt)
        acc[mt][nt] = MFMA16F(af[mt], bf, acc[mt][nt]);
    }
  }
#pragma unroll
  for (int mt = 0; mt < 4; ++mt)
#pragma unroll
    for (int nt = 0; nt < 4; ++nt)
#pragma unroll
      for (int r = 0; r < 4; ++r) {
        int row = m0 + wm + mt * 16 + 4 * g + r;
        int col = n0 + wn + nt * 16 + li;
        C[(size_t)row * DM + col] = acc[mt][nt][r];
      }
}

extern "C" void kernel_launch(void* const* d_in, const int* in_sizes, int n_in,
                              void* d_out, int out_size, void* d_ws, size_t ws_size,
                              hipStream_t stream) {
  const float* x     = (const float*)d_in[0];
  const float* gamma = (const float*)d_in[1];
  const float* wqkv  = (const float*)d_in[2];
  const float* wout  = (const float*)d_in[3];
  float* out = (float*)d_out;

  char* ws = (char*)d_ws;
  size_t off = 0;
  auto alloc = [&](size_t n) { char* p = ws + off; off += (n + 255) & ~(size_t)255; return p; };

  unsigned short* xh  = (unsigned short*)alloc((size_t)NT * DM * 2);
  unsigned short* wqh = (unsigned short*)alloc((size_t)NB * DM * 2);
  unsigned short* qhp = (unsigned short*)alloc((size_t)NH * NT * DH * 2);
  unsigned short* khp = (unsigned short*)alloc((size_t)NH * NT * DH * 2);
  unsigned short* vvT = (unsigned short*)alloc((size_t)NH * DH * NT * 2);
  unsigned short* ao  = (unsigned short*)alloc((size_t)NT * DM * 2);
  unsigned short* woT = (unsigned short*)alloc((size_t)DM * DM * 2);
  float*          prt = (float*)alloc((size_t)NH * 52 * PARTB);  // fp16 O + f32 m,l
  (void)ws_size; (void)in_sizes; (void)n_in; (void)out_size;

  k_transpose_half<<<dim3(DM / 64, NB / 64), 256, 0, stream>>>(wqkv, DM, NB, wqh);
  k_transpose_half<<<dim3(DM / 64, DM / 64), 256, 0, stream>>>(wout, DM, DM, woT);
  k_rmsnorm_half<<<NT, 256, 0, stream>>>(x, gamma, xh);
  k_qkv_gemm<<<dim3(NB / 128, NT / 128), 256, 0, stream>>>(xh, wqh, qhp, khp, vvT);
  k_attn<<<1008, 256, 0, stream>>>(qhp, khp, vvT, ao, prt);
  k_merge<<<16 * 21, 256, 0, stream>>>(prt, ao);
  k_out_gemm<<<dim3(DM / 128, NT / 128), 256, 0, stream>>>(ao, woT, out);
}

// Round 18
// 183.692 us; speedup vs baseline: 1.0463x; 1.0457x over previous
//
#include <hip/hip_runtime.h>
#include <stdint.h>

typedef __attribute__((ext_vector_type(8))) _Float16 f16x8;
typedef __attribute__((ext_vector_type(4))) float f32x4;
typedef __attribute__((ext_vector_type(16))) float f32x16;

#define MFMA16F(a, b, c) __builtin_amdgcn_mfma_f32_16x16x32_f16((a), (b), (c), 0, 0, 0)
#define MFMA32F(a, b, c) __builtin_amdgcn_mfma_f32_32x32x16_f16((a), (b), (c), 0, 0, 0)

static constexpr int NT = 4096;   // tokens
static constexpr int DM = 1024;   // model dim
static constexpr int NH = 16;     // heads
static constexpr int DH = 64;     // head dim
static constexpr int NB = 3072;   // qkv output cols
static constexpr int PARTB = 128 * 64 * 2 + 1024;  // bytes/partial: fp16 O + f32 m,l

__device__ __forceinline__ unsigned short f2h(float f) {
  union { _Float16 h; unsigned short u; } v; v.h = (_Float16)f; return v.u;
}
__device__ __forceinline__ float h2f(unsigned short u) {
  union { _Float16 h; unsigned short u; } v; v.u = u; return (float)v.h;
}
__device__ __forceinline__ f32x16 zero16() {
  f32x16 z;
#pragma unroll
  for (int i = 0; i < 16; ++i) z[i] = 0.f;
  return z;
}
// direct global->LDS 16B copy (lane i lands at ldsbase + i*16)
__device__ __forceinline__ void gl2lds16(const void* g, void* l) {
  auto gp = (const __attribute__((address_space(1))) uint32_t*)(uintptr_t)g;
  auto lp = (__attribute__((address_space(3))) uint32_t*)(uint32_t)(uintptr_t)l;
  __builtin_amdgcn_global_load_lds(gp, lp, 16, 0, 0);
}
// swizzled byte offset inside a [128][32]-fp16 linear tile
__device__ __forceinline__ int swzoff(int row, int g) {
  return row * 64 + (((g ^ (row >> 1)) & 3) << 4);
}

// ---------------- transpose fp32 weights -> fp16 [N][K] ----------------
__global__ __launch_bounds__(256) void k_transpose_half(
    const float* __restrict__ src, int K, int N, unsigned short* __restrict__ dst) {
  __shared__ float tile[64][65];
  const int tk = blockIdx.x * 64;
  const int tn = blockIdx.y * 64;
  const int t = threadIdx.x;
  const int rr = t >> 4, cc = (t & 15) * 4;
#pragma unroll
  for (int p = 0; p < 4; ++p) {
    int r = rr + p * 16;
    const float4 v = *reinterpret_cast<const float4*>(&src[(size_t)(tk + r) * N + tn + cc]);
    tile[r][cc] = v.x; tile[r][cc + 1] = v.y; tile[r][cc + 2] = v.z; tile[r][cc + 3] = v.w;
  }
  __syncthreads();
#pragma unroll
  for (int p = 0; p < 4; ++p) {
    int r = rr + p * 16;  // n offset
    size_t o = (size_t)(tn + r) * K + tk + cc;
    *reinterpret_cast<ushort4*>(&dst[o]) =
        make_ushort4(f2h(tile[cc + 0][r]), f2h(tile[cc + 1][r]),
                     f2h(tile[cc + 2][r]), f2h(tile[cc + 3][r]));
  }
}

// ---------------- RMSNorm (L2-normalize * sqrt(dim) * gamma) -> fp16 ----------------
__global__ __launch_bounds__(256) void k_rmsnorm_half(
    const float* __restrict__ x, const float* __restrict__ gamma,
    unsigned short* __restrict__ xh) {
  const int row = blockIdx.x;
  const int t = threadIdx.x;
  const float4 v = reinterpret_cast<const float4*>(x + (size_t)row * DM)[t];
  float ss = v.x * v.x + v.y * v.y + v.z * v.z + v.w * v.w;
#pragma unroll
  for (int m = 1; m <= 32; m <<= 1) ss += __shfl_xor(ss, m);
  __shared__ float red[4];
  if ((t & 63) == 0) red[t >> 6] = ss;
  __syncthreads();
  float tot = red[0] + red[1] + red[2] + red[3];
  float inv = 32.0f * rsqrtf(fmaxf(tot, 1e-24f));
  const float4 g = reinterpret_cast<const float4*>(gamma)[t];
  *reinterpret_cast<ushort4*>(&xh[(size_t)row * DM + t * 4]) =
      make_ushort4(f2h(v.x * inv * g.x), f2h(v.y * inv * g.y),
                   f2h(v.z * inv * g.z), f2h(v.w * inv * g.w));
}

// ---------------- QKV GEMM: plain fp16; global_load_lds staging, swizzled LDS ----------
__global__ __launch_bounds__(256) void k_qkv_gemm(
    const unsigned short* __restrict__ xh, const unsigned short* __restrict__ wh,
    unsigned short* __restrict__ qh, unsigned short* __restrict__ kh,
    unsigned short* __restrict__ vvT) {
  __shared__ unsigned short sA[128 * 32], sB[128 * 32];
  const int t = threadIdx.x;
  const int l = t & 63, w = t >> 6;
  const int g = l >> 4, li = l & 15;
  const int m0 = blockIdx.y * 128, n0 = blockIdx.x * 128;
  const int wm = (w >> 1) * 64, wn = (w & 1) * 64;

  int srow[2], scol[2];
#pragma unroll
  for (int j = 0; j < 2; ++j) {
    int slot = w * 128 + j * 64 + l;
    srow[j] = slot >> 2;
    scol[j] = (((slot & 3) ^ (srow[j] >> 1)) & 3) * 8;
  }
  const int lb0 = __builtin_amdgcn_readfirstlane(w * 2048);  // wave-uniform LDS byte base

  f32x4 acc[4][4];
#pragma unroll
  for (int a = 0; a < 4; ++a)
#pragma unroll
    for (int b = 0; b < 4; ++b) acc[a][b] = f32x4{0.f, 0.f, 0.f, 0.f};

  for (int k0 = 0; k0 < DM; k0 += 32) {
    __syncthreads();  // previous compute's LDS reads done
#pragma unroll
    for (int j = 0; j < 2; ++j) {
      const int lb = lb0 + j * 1024;
      gl2lds16(&xh[(size_t)(m0 + srow[j]) * DM + k0 + scol[j]], (char*)sA + lb);
      gl2lds16(&wh[(size_t)(n0 + srow[j]) * DM + k0 + scol[j]], (char*)sB + lb);
    }
    __syncthreads();  // barrier drain -> tile visible
    f16x8 af[4];
#pragma unroll
    for (int mt = 0; mt < 4; ++mt)
      af[mt] = *(const f16x8*)((const char*)sA + swzoff(wm + mt * 16 + li, g));
#pragma unroll
    for (int nt = 0; nt < 4; ++nt) {
      f16x8 bf = *(const f16x8*)((const char*)sB + swzoff(wn + nt * 16 + li, g));
#pragma unroll
      for (int mt = 0; mt < 4; ++mt)
        acc[mt][nt] = MFMA16F(af[mt], bf, acc[mt][nt]);
    }
  }
  // epilogue: C/D layout col=lane&15, row=4*(lane>>4)+reg
#pragma unroll
  for (int mt = 0; mt < 4; ++mt)
#pragma unroll
    for (int nt = 0; nt < 4; ++nt)
#pragma unroll
      for (int r = 0; r < 4; ++r) {
        int row = m0 + wm + mt * 16 + 4 * g + r;
        int col = n0 + wn + nt * 16 + li;
        float val = acc[mt][nt][r];
        int which = col >> 10;
        int head = (col >> 6) & 15;
        int d = col & 63;
        if (which == 0) {
          // fold sqrt(dim_head)=8 AND log2(e) so softmax uses exp2
          qh[((size_t)head * NT + row) * DH + d] = f2h(val * 11.5415603f);
        } else if (which == 1) {
          kh[((size_t)head * NT + row) * DH + d] = f2h(val);
        } else {
          vvT[((size_t)head * DH + d) * NT + row] = f2h(val);  // [h][d][n]
        }
      }
}

// ---------------- causal flash attention: 32x32 fp16 MFMA, 128-q tiles, chunked KV -----
// 1008 blocks = 16 heads x 63 chunks (R12-proven schedule). Reg-prefetch staging.
__global__ __launch_bounds__(256) void k_attn(
    const unsigned short* __restrict__ qh, const unsigned short* __restrict__ kh,
    const unsigned short* __restrict__ vvT, unsigned short* __restrict__ oo,
    float* __restrict__ part) {
  __shared__ unsigned short sKh[64 * 64], sVt[64 * 64];
  const int t = threadIdx.x;
  const int l = t & 63, w = t >> 6;
  const int hl = l >> 5, l31 = l & 31;
  const int bid = blockIdx.x;
  const int hh = (bid & 7) * 2 + ((bid >> 3) & 1);  // 2 heads per XCD
  const int r = bid >> 4;                            // 0..62
  int qt, j, P;
  if (r < 11)      { qt = r;                 j = 0;            P = 1; }
  else if (r < 33) { qt = 11 + (r - 11) / 2; j = (r - 11) & 1; P = 2; }
  else             { qt = 22 + (r - 33) / 3; j = (r - 33) % 3; P = 3; }
  const int n = 2 * qt + 2;
  const int kb0 = (j * n) / P, kb1 = ((j + 1) * n) / P - 1;
  const int q0 = qt * 128;
  const int qrow = q0 + w * 32 + l31;

  // Q fragments: lane(col=q=l31, half hl) supplies d = 16c + 8*hl + j
  size_t qoff = ((size_t)hh * NT + qrow) * DH;
  f16x8 qf[4];
#pragma unroll
  for (int c = 0; c < 4; ++c)
    qf[c] = *(const f16x8*)&qh[qoff + c * 16 + hl * 8];

  f32x16 oacc[2];
  oacc[0] = zero16(); oacc[1] = zero16();
  float mrun = -INFINITY, lsum = 0.f;

  // staging: 2 chunks/thread/array; chunk ch: row=ch>>3, slot=ch&7
  f16x8 rk[2], rv[2];
  const int srow0 = t >> 3, srow1 = (t + 256) >> 3, sslot = t & 7;
  auto LOAD = [&](int kb) {
    const int kv0 = kb * 64;
    rk[0] = *(const f16x8*)&kh[((size_t)hh * NT + kv0 + srow0) * DH + sslot * 8];
    rk[1] = *(const f16x8*)&kh[((size_t)hh * NT + kv0 + srow1) * DH + sslot * 8];
    rv[0] = *(const f16x8*)&vvT[((size_t)hh * DH + srow0) * NT + kv0 + sslot * 8];
    rv[1] = *(const f16x8*)&vvT[((size_t)hh * DH + srow1) * NT + kv0 + sslot * 8];
  };
  const int lw0 = srow0 * 128 + ((sslot ^ (srow0 & 7)) * 16);
  const int lw1 = srow1 * 128 + ((sslot ^ (srow1 & 7)) * 16);

  LOAD(kb0);
  for (int kb = kb0; kb <= kb1; ++kb) {
    const int kv0 = kb * 64;
    __syncthreads();
    *(f16x8*)((char*)sKh + lw0) = rk[0];  *(f16x8*)((char*)sKh + lw1) = rk[1];
    *(f16x8*)((char*)sVt + lw0) = rv[0];  *(f16x8*)((char*)sVt + lw1) = rv[1];
    __syncthreads();
    if (kb < kb1) LOAD(kb + 1);

    if (kv0 > q0 + w * 32 + 31) continue;  // wave entirely above diagonal

    // S^T = K * Q^T: C/D col=q=l31, row(kv-in-32)=(reg&3)+8*(reg>>2)+4*hl
    f32x16 s[2];
#pragma unroll
    for (int kvt = 0; kvt < 2; ++kvt) {
      f32x16 sv = zero16();
      const int rowk = kvt * 32 + l31;
      const int rb = rowk * 128;
#pragma unroll
      for (int c = 0; c < 4; ++c) {
        const int sl = ((2 * c + hl) ^ (rowk & 7)) * 16;
        f16x8 ah = *(const f16x8*)((const char*)sKh + rb + sl);
        sv = MFMA32F(ah, qf[c], sv);
      }
      s[kvt] = sv;
    }
    if (kv0 + 63 > q0 + w * 32) {  // wave touches diagonal iff max kv > MIN q-row
#pragma unroll
      for (int kvt = 0; kvt < 2; ++kvt)
#pragma unroll
        for (int reg = 0; reg < 16; ++reg) {
          int kv = kv0 + kvt * 32 + (reg & 3) + 8 * (reg >> 2) + 4 * hl;
          if (kv > qrow) s[kvt][reg] = -INFINITY;
        }
    }
    // lane-local online softmax (log2 domain); partner lane l^32 holds same q
    float vmax = -INFINITY;
#pragma unroll
    for (int kvt = 0; kvt < 2; ++kvt)
#pragma unroll
      for (int reg = 0; reg < 16; ++reg) vmax = fmaxf(vmax, s[kvt][reg]);
    vmax = fmaxf(vmax, __shfl_xor(vmax, 32));
    float mnew;
    if (mrun != -INFINITY && vmax <= mrun + 11.0f) {
      mnew = mrun;  // defer-max: skip rescale, P bounded by 2^11
    } else {
      mnew = fmaxf(mrun, vmax);
      float sc = exp2f(mrun - mnew);
      lsum *= sc;
#pragma unroll
      for (int dt = 0; dt < 2; ++dt)
#pragma unroll
        for (int reg = 0; reg < 16; ++reg) oacc[dt][reg] *= sc;
      mrun = mnew;
    }
    float ps = 0.f;
#pragma unroll
    for (int kvt = 0; kvt < 2; ++kvt)
#pragma unroll
      for (int reg = 0; reg < 16; ++reg) {
        float pv = exp2f(s[kvt][reg] - mnew);
        s[kvt][reg] = pv;
        ps += pv;
      }
    ps += __shfl_xor(ps, 32);
    lsum += ps;

    // P fragments (pi-packing): chunk c slot j <-> kv = 16c + 4*hl + (j&3) + 8*(j>>2)
    union U8 { _Float16 e[8]; f16x8 v; } pf[4];
#pragma unroll
    for (int c = 0; c < 4; ++c)
#pragma unroll
      for (int jj = 0; jj < 8; ++jj)
        pf[c].e[jj] = (_Float16)s[c >> 1][(jj & 3) + 4 * (jj >> 2) + 8 * (c & 1)];

    // O^T += V^T * P^T: A = V^T (row=d=l31), same pi k-mapping -> two b64 per chunk
#pragma unroll
    for (int dt = 0; dt < 2; ++dt) {
      const int rowv = dt * 32 + l31;
      const int rb = rowv * 128;
#pragma unroll
      for (int c = 0; c < 4; ++c) {
        const int s0 = (((2 * c) ^ (rowv & 7)) * 16) + 8 * hl;
        const int s1 = (((2 * c + 1) ^ (rowv & 7)) * 16) + 8 * hl;
        union U8 vf;
        *(ushort4*)&vf.e[0] = *(const ushort4*)((const char*)sVt + rb + s0);
        *(ushort4*)&vf.e[4] = *(const ushort4*)((const char*)sVt + rb + s1);
        oacc[dt] = MFMA32F(vf.v, pf[c].v, oacc[dt]);
      }
    }
  }
  // epilogue: O^T lane: col=q=l31, row d = dt*32 + 4*hl + 8*rr + (0..3)
  if (P == 1) {
    float inv = 1.0f / lsum;
#pragma unroll
    for (int dt = 0; dt < 2; ++dt)
#pragma unroll
      for (int rr = 0; rr < 4; ++rr) {
        ushort4 o4 = make_ushort4(f2h(oacc[dt][4 * rr + 0] * inv), f2h(oacc[dt][4 * rr + 1] * inv),
                                  f2h(oacc[dt][4 * rr + 2] * inv), f2h(oacc[dt][4 * rr + 3] * inv));
        *(ushort4*)&oo[(size_t)qrow * DM + hh * 64 + dt * 32 + 8 * rr + 4 * hl] = o4;
      }
  } else {
    const int sb = (qt <= 21) ? (qt - 11) * 2 : 22 + (qt - 22) * 3;  // compact slots
    char* pb = (char*)part + (size_t)(hh * 52 + sb + j) * PARTB;
    unsigned short* po = (unsigned short*)pb;
    float* pm = (float*)(pb + 16384);
    const int qr = w * 32 + l31;
#pragma unroll
    for (int dt = 0; dt < 2; ++dt)
#pragma unroll
      for (int rr = 0; rr < 4; ++rr) {
        ushort4 o4 = make_ushort4(f2h(oacc[dt][4 * rr + 0]), f2h(oacc[dt][4 * rr + 1]),
                                  f2h(oacc[dt][4 * rr + 2]), f2h(oacc[dt][4 * rr + 3]));
        *(ushort4*)&po[qr * 64 + dt * 32 + 8 * rr + 4 * hl] = o4;
      }
    if (hl == 0) { pm[qr] = mrun; pm[128 + qr] = lsum; }
  }
}

// ---------------- merge KV-chunk partials for tiles qt in [11,31] ----------------
__global__ __launch_bounds__(256) void k_merge(const float* __restrict__ part,
                                               unsigned short* __restrict__ oo) {
  const int mb = blockIdx.x;  // 16 heads x 21 tiles
  const int hh = mb / 21, qt = 11 + mb % 21;
  const int P = (qt <= 21) ? 2 : 3;
  const int sb = (qt <= 21) ? (qt - 11) * 2 : 22 + (qt - 22) * 3;
  const char* base = (const char*)part + (size_t)(hh * 52 + sb) * PARTB;
  const int t = threadIdx.x;
  const int row = t >> 1, d0 = (t & 1) * 32;
  float mm = -INFINITY;
  for (int p = 0; p < P; ++p)
    mm = fmaxf(mm, *(const float*)(base + p * PARTB + 16384 + row * 4));
  float denom = 0.f;
  for (int p = 0; p < P; ++p) {
    float mp = *(const float*)(base + p * PARTB + 16384 + row * 4);
    float lp = *(const float*)(base + p * PARTB + 16384 + 512 + row * 4);
    denom += exp2f(mp - mm) * lp;
  }
  float inv = 1.0f / denom;
  const size_t orow = (size_t)(qt * 128 + row) * DM + hh * 64 + d0;
#pragma unroll
  for (int dd = 0; dd < 32; dd += 4) {
    float a0 = 0, a1 = 0, a2 = 0, a3 = 0;
    for (int p = 0; p < P; ++p) {
      float wp = exp2f(*(const float*)(base + p * PARTB + 16384 + row * 4) - mm);
      ushort4 u = *(const ushort4*)(base + p * PARTB + (size_t)(row * 64 + d0 + dd) * 2);
      a0 += wp * h2f(u.x); a1 += wp * h2f(u.y); a2 += wp * h2f(u.z); a3 += wp * h2f(u.w);
    }
    *(ushort4*)&oo[orow + dd] = make_ushort4(f2h(a0 * inv), f2h(a1 * inv),
                                             f2h(a2 * inv), f2h(a3 * inv));
  }
}

// ---------------- out projection: fp16, global_load_lds staging, swizzled LDS ----------
__global__ __launch_bounds__(256) void k_out_gemm(
    const unsigned short* __restrict__ A, const unsigned short* __restrict__ Bt,
    float* __restrict__ C) {
  __shared__ unsigned short sA[128 * 32], sB[128 * 32];
  const int t = threadIdx.x;
  const int l = t & 63, w = t >> 6;
  const int g = l >> 4, li = l & 15;
  const int m0 = blockIdx.y * 128, n0 = blockIdx.x * 128;
  const int wm = (w >> 1) * 64, wn = (w & 1) * 64;

  int srow[2], scol[2];
#pragma unroll
  for (int j = 0; j < 2; ++j) {
    int slot = w * 128 + j * 64 + l;
    srow[j] = slot >> 2;
    scol[j] = (((slot & 3) ^ (srow[j] >> 1)) & 3) * 8;
  }
  const int lb0 = __builtin_amdgcn_readfirstlane(w * 2048);

  f32x4 acc[4][4];
#pragma unroll
  for (int a = 0; a < 4; ++a)
#pragma unroll
    for (int b = 0; b < 4; ++b) acc[a][b] = f32x4{0.f, 0.f, 0.f, 0.f};

  for (int k0 = 0; k0 < DM; k0 += 32) {
    __syncthreads();
#pragma unroll
    for (int j = 0; j < 2; ++j) {
      const int lb = lb0 + j * 1024;
      gl2lds16(&A[(size_t)(m0 + srow[j]) * DM + k0 + scol[j]], (char*)sA + lb);
      gl2lds16(&Bt[(size_t)(n0 + srow[j]) * DM + k0 + scol[j]], (char*)sB + lb);
    }
    __syncthreads();
    f16x8 af[4];
#pragma unroll
    for (int mt = 0; mt < 4; ++mt)
      af[mt] = *(const f16x8*)((const char*)sA + swzoff(wm + mt * 16 + li, g));
#pragma unroll
    for (int nt = 0; nt < 4; ++nt) {
      f16x8 bf = *(const f16x8*)((const char*)sB + swzoff(wn + nt * 16 + li, g));
#pragma unroll
      for (int mt = 0; mt < 4; ++mt)
        acc[mt][nt] = MFMA16F(af[mt], bf, acc[mt][nt]);
    }
  }
#pragma unroll
  for (int mt = 0; mt < 4; ++mt)
#pragma unroll
    for (int nt = 0; nt < 4; ++nt)
#pragma unroll
      for (int r = 0; r < 4; ++r) {
        int row = m0 + wm + mt * 16 + 4 * g + r;
        int col = n0 + wn + nt * 16 + li;
        C[(size_t)row * DM + col] = acc[mt][nt][r];
      }
}

extern "C" void kernel_launch(void* const* d_in, const int* in_sizes, int n_in,
                              void* d_out, int out_size, void* d_ws, size_t ws_size,
                              hipStream_t stream) {
  const float* x     = (const float*)d_in[0];
  const float* gamma = (const float*)d_in[1];
  const float* wqkv  = (const float*)d_in[2];
  const float* wout  = (const float*)d_in[3];
  float* out = (float*)d_out;

  char* ws = (char*)d_ws;
  size_t off = 0;
  auto alloc = [&](size_t n) { char* p = ws + off; off += (n + 255) & ~(size_t)255; return p; };

  unsigned short* xh  = (unsigned short*)alloc((size_t)NT * DM * 2);
  unsigned short* wqh = (unsigned short*)alloc((size_t)NB * DM * 2);
  unsigned short* qhp = (unsigned short*)alloc((size_t)NH * NT * DH * 2);
  unsigned short* khp = (unsigned short*)alloc((size_t)NH * NT * DH * 2);
  unsigned short* vvT = (unsigned short*)alloc((size_t)NH * DH * NT * 2);
  unsigned short* ao  = (unsigned short*)alloc((size_t)NT * DM * 2);
  unsigned short* woT = (unsigned short*)alloc((size_t)DM * DM * 2);
  float*          prt = (float*)alloc((size_t)NH * 52 * PARTB);  // fp16 O + f32 m,l
  (void)ws_size; (void)in_sizes; (void)n_in; (void)out_size;

  k_transpose_half<<<dim3(DM / 64, NB / 64), 256, 0, stream>>>(wqkv, DM, NB, wqh);
  k_transpose_half<<<dim3(DM / 64, DM / 64), 256, 0, stream>>>(wout, DM, DM, woT);
  k_rmsnorm_half<<<NT, 256, 0, stream>>>(x, gamma, xh);
  k_qkv_gemm<<<dim3(NB / 128, NT / 128), 256, 0, stream>>>(xh, wqh, qhp, khp, vvT);
  k_attn<<<1008, 256, 0, stream>>>(qhp, khp, vvT, ao, prt);
  k_merge<<<16 * 21, 256, 0, stream>>>(prt, ao);
  k_out_gemm<<<dim3(DM / 128, NT / 128), 256, 0, stream>>>(ao, woT, out);
}